// Round 8
// baseline (188.120 us; speedup 1.0000x reference)
//
#include <hip/hip_runtime.h>
#include <math.h>

#define B_ 4
#define S_ 2048
#define D_ 512
#define H_ 8
#define DH_ 64
#define BH_ (B_*H_)
#define SCALE 0.1803368801111243f   // log2(e)/sqrt(64)

typedef __attribute__((ext_vector_type(4)))  float f32x4;
typedef __attribute__((ext_vector_type(16))) float f32x16;
typedef __attribute__((ext_vector_type(8)))  short bf16x8;
typedef __attribute__((ext_vector_type(4)))  uint  u32x4;

__device__ inline uint rnepk(float a, float b) {
    uint ua = __builtin_bit_cast(uint, a), ub = __builtin_bit_cast(uint, b);
    ua += 0x7FFFu + ((ua >> 16) & 1u);
    ub += 0x7FFFu + ((ub >> 16) & 1u);
    return (ua >> 16) | (ub & 0xFFFF0000u);
}
__device__ inline uint truncpk(float lo, float hi) {   // 1 v_perm_b32
    return __builtin_amdgcn_perm(__builtin_bit_cast(uint, hi),
                                 __builtin_bit_cast(uint, lo), 0x07060302u);
}
__device__ inline f32x16 zero16() {
    f32x16 z;
    #pragma unroll
    for (int i = 0; i < 16; ++i) z[i] = 0.f;
    return z;
}
__device__ inline bf16x8 pack8(f32x4 a, f32x4 c) {
    u32x4 u;
    u.x = rnepk(a[0], a[1]); u.y = rnepk(a[2], a[3]);
    u.z = rnepk(c[0], c[1]); u.w = rnepk(c[2], c[3]);
    return __builtin_bit_cast(bf16x8, u);
}

// (lane,lane^32) quad exchange (validated via the P-transform in R6)
#if __has_builtin(__builtin_amdgcn_permlane32_swap)
__device__ inline void lane32swap(uint& a, uint& b) {
    typedef __attribute__((ext_vector_type(2))) uint u32x2;
    u32x2 r = __builtin_amdgcn_permlane32_swap(a, b, false, false);
    a = r.x; b = r.y;
}
#else
__device__ inline void lane32swap(uint& a, uint& b) {
    const int l5 = (threadIdx.x & 63) >> 5;
    uint send = l5 ? a : b;
    uint recv = __shfl_xor(send, 32);
    uint an = l5 ? recv : a;
    uint bn = l5 ? b : recv;
    a = an; b = bn;
}
#endif

// ---------------------------------------------------------------------------
// Fused MSA: grid 512 = 32 bh x 16 q-chunks, 256 thr, 2 blocks/CU (all
// co-resident: __launch_bounds__(256,2) -> >=512 slots). Phase 1: block
// projects keys [qc*128, qc*128+128) -> Kb/Vtg (global ws), arrival on
// cnt[bh]; projects its own 128-row Q-tile in-register (C->B-frag via
// lane32swap). Phase 2: spin until cnt[bh]==16, fence, then the R6 flash
// body (double-buffered K/V, P via permlane swap, 1 barrier/kt).
// ---------------------------------------------------------------------------
__global__ __launch_bounds__(256, 2)
void msa_fused(const float* __restrict__ x,
               const float* __restrict__ Wq, const float* __restrict__ bq,
               const float* __restrict__ Wk, const float* __restrict__ bk,
               const float* __restrict__ Wv, const float* __restrict__ bv,
               ushort* __restrict__ Kb, ushort* __restrict__ Vtg,
               uint* __restrict__ cnt, float* __restrict__ out)
{
    const int blk = blockIdx.x;
    const int bh = blk & 31, qblk = blk >> 5;
    const int b = bh >> 3, h = bh & 7;
    const int tid = threadIdx.x;
    const int w = tid >> 6, lane = tid & 63, l31 = lane & 31, l5 = lane >> 5;
    const int s0 = qblk * 128;

    __shared__ __align__(16) ushort lds_u[17408];
    ushort* mybnc = lds_u + w * 2560;

    // =================== phase 1: projection ===================
    const int srow = w * 32 + l31;
    const float* xr = x + ((size_t)(b * S_ + s0 + srow)) * D_ + h * DH_;
    bf16x8 xf[4];
    #pragma unroll
    for (int st = 0; st < 4; ++st) {
        f32x4 a = *(const f32x4*)(xr + st * 16 + l5 * 8);
        f32x4 c = *(const f32x4*)(xr + st * 16 + l5 * 8 + 4);
        xf[st] = pack8(a, c);
    }

    // ---- K: C[e][s] (A=Wk, B=x) -> bounce [s][e] -> Kb coalesced ----
    {
        bf16x8 wf[2][4];
        #pragma unroll
        for (int et = 0; et < 2; ++et) {
            const float* wr = Wk + h * DH_ * DH_ + (et * 32 + l31) * DH_;
            #pragma unroll
            for (int st = 0; st < 4; ++st)
                wf[et][st] = pack8(*(const f32x4*)(wr + st * 16 + l5 * 8),
                                   *(const f32x4*)(wr + st * 16 + l5 * 8 + 4));
        }
        #pragma unroll
        for (int et = 0; et < 2; ++et) {
            f32x16 acc = zero16();
            #pragma unroll
            for (int st = 0; st < 4; ++st)
                acc = __builtin_amdgcn_mfma_f32_32x32x16_bf16(wf[et][st], xf[st], acc, 0, 0, 0);
            #pragma unroll
            for (int rg = 0; rg < 4; ++rg) {
                float4 b4 = *(const float4*)(bk + h * DH_ + et * 32 + rg * 8 + l5 * 4);
                uint2 pk;
                pk.x = rnepk(acc[rg * 4 + 0] + b4.x, acc[rg * 4 + 1] + b4.y);
                pk.y = rnepk(acc[rg * 4 + 2] + b4.z, acc[rg * 4 + 3] + b4.w);
                *(uint2*)(mybnc + l31 * 72 + et * 32 + rg * 8 + l5 * 4) = pk;
            }
        }
        #pragma unroll
        for (int i = 0; i < 4; ++i) {
            const int slot = lane + 64 * i;
            const int r = slot >> 3, c = slot & 7;
            uint4 v = *(const uint4*)(mybnc + r * 72 + c * 8);
            *(uint4*)(Kb + ((size_t)(bh * S_ + s0 + w * 32 + r)) * DH_ + c * 8) = v;
        }
    }

    // ---- V: C[s][e] (A=x, B=Wv) -> bounce [e][s] -> Vtg coalesced ----
    {
        bf16x8 wf[2][4];
        #pragma unroll
        for (int et = 0; et < 2; ++et) {
            const float* wr = Wv + h * DH_ * DH_ + (et * 32 + l31) * DH_;
            #pragma unroll
            for (int st = 0; st < 4; ++st)
                wf[et][st] = pack8(*(const f32x4*)(wr + st * 16 + l5 * 8),
                                   *(const f32x4*)(wr + st * 16 + l5 * 8 + 4));
        }
        #pragma unroll
        for (int et = 0; et < 2; ++et) {
            f32x16 acc = zero16();
            #pragma unroll
            for (int st = 0; st < 4; ++st)
                acc = __builtin_amdgcn_mfma_f32_32x32x16_bf16(xf[st], wf[et][st], acc, 0, 0, 0);
            const float bb = bv[h * DH_ + et * 32 + l31];
            #pragma unroll
            for (int rg = 0; rg < 4; ++rg) {
                uint2 pk;
                pk.x = rnepk(acc[rg * 4 + 0] + bb, acc[rg * 4 + 1] + bb);
                pk.y = rnepk(acc[rg * 4 + 2] + bb, acc[rg * 4 + 3] + bb);
                *(uint2*)(mybnc + (et * 32 + l31) * 40 + rg * 8 + l5 * 4) = pk;
            }
        }
        #pragma unroll
        for (int i = 0; i < 4; ++i) {
            const int slot = lane + 64 * i;
            const int r = slot >> 2, c = slot & 3;
            uint4 v = *(const uint4*)(mybnc + r * 40 + c * 8);
            *(uint4*)(Vtg + ((size_t)(bh * DH_ + r)) * S_ + s0 + w * 32 + c * 8) = v;
        }
    }

    __syncthreads();                      // drains all waves' vmem stores
    if (tid == 0) {
        __threadfence();                  // release: K/V visible device-wide
        __hip_atomic_fetch_add(&cnt[bh], 1u, __ATOMIC_RELAXED,
                               __HIP_MEMORY_SCOPE_AGENT);
    }

    // ---- Q (overlaps sibling stragglers): C[e][s] -> B-frags in-register ----
    bf16x8 qf[4];
    {
        bf16x8 wf[2][4];
        #pragma unroll
        for (int et = 0; et < 2; ++et) {
            const float* wr = Wq + h * DH_ * DH_ + (et * 32 + l31) * DH_;
            #pragma unroll
            for (int st = 0; st < 4; ++st)
                wf[et][st] = pack8(*(const f32x4*)(wr + st * 16 + l5 * 8),
                                   *(const f32x4*)(wr + st * 16 + l5 * 8 + 4));
        }
        #pragma unroll
        for (int et = 0; et < 2; ++et) {
            f32x16 acc = zero16();
            #pragma unroll
            for (int st = 0; st < 4; ++st)
                acc = __builtin_amdgcn_mfma_f32_32x32x16_bf16(wf[et][st], xf[st], acc, 0, 0, 0);
            uint qr[8];
            #pragma unroll
            for (int rg = 0; rg < 4; ++rg) {
                float4 b4 = *(const float4*)(bq + h * DH_ + et * 32 + rg * 8 + l5 * 4);
                qr[2 * rg + 0] = rnepk((acc[rg * 4 + 0] + b4.x) * SCALE,
                                       (acc[rg * 4 + 1] + b4.y) * SCALE);
                qr[2 * rg + 1] = rnepk((acc[rg * 4 + 2] + b4.z) * SCALE,
                                       (acc[rg * 4 + 3] + b4.w) * SCALE);
            }
            #pragma unroll
            for (int p = 0; p < 2; ++p) {       // same exchange as P-transform
                lane32swap(qr[4 * p + 0], qr[4 * p + 2]);
                lane32swap(qr[4 * p + 1], qr[4 * p + 3]);
                u32x4 u; u.x = qr[4 * p + 0]; u.y = qr[4 * p + 1];
                u.z = qr[4 * p + 2]; u.w = qr[4 * p + 3];
                qf[et * 2 + p] = __builtin_bit_cast(bf16x8, u);
            }
        }
    }

    // ---- wait for all 16 producer blocks of this bh ----
    if (tid == 0) {
        while (__hip_atomic_load(&cnt[bh], __ATOMIC_RELAXED,
                                 __HIP_MEMORY_SCOPE_AGENT) < 16u)
            __builtin_amdgcn_s_sleep(2);
    }
    __syncthreads();
    __threadfence();                      // acquire: see siblings' K/V

    // =================== phase 2: flash (R6 body) ===================
    const int q0 = s0 + w * 32;           // this wave's q rows
    f32x16 O[2];
    O[0] = zero16(); O[1] = zero16();
    float lsum = 0.f;

    const ushort* kg = Kb + (size_t)bh * S_ * DH_;
    const ushort* vg = Vtg + (size_t)bh * DH_ * S_;
    const int sr0 = tid >> 3, sc = tid & 7, sr1 = sr0 + 32;
    const int swz0 = (sc ^ (sr0 & 7)) * 8, swz1 = (sc ^ (sr1 & 7)) * 8;

    {   // prologue: stage kt=0 into buffer 0
        uint4 k0 = *(const uint4*)(kg + (size_t)sr0 * DH_ + sc * 8);
        uint4 k1 = *(const uint4*)(kg + (size_t)sr1 * DH_ + sc * 8);
        uint4 v0 = *(const uint4*)(vg + (size_t)sr0 * S_ + sc * 8);
        uint4 v1 = *(const uint4*)(vg + (size_t)sr1 * S_ + sc * 8);
        *(uint4*)(lds_u + sr0 * 64 + swz0) = k0;
        *(uint4*)(lds_u + sr1 * 64 + swz1) = k1;
        *(uint4*)(lds_u + 8192 + sr0 * 64 + swz0) = v0;
        *(uint4*)(lds_u + 8192 + sr1 * 64 + swz1) = v1;
    }

    for (int kt = 0; kt < 32; ++kt) {
        __syncthreads();
        const int cur = kt & 1, nxt = cur ^ 1;
        uint4 kv0, kv1, vv0, vv1;
        if (kt < 31) {
            const size_t ko = (size_t)(kt + 1) * 64 * DH_;
            const int vo = (kt + 1) * 64;
            kv0 = *(const uint4*)(kg + ko + (size_t)sr0 * DH_ + sc * 8);
            kv1 = *(const uint4*)(kg + ko + (size_t)sr1 * DH_ + sc * 8);
            vv0 = *(const uint4*)(vg + (size_t)sr0 * S_ + vo + sc * 8);
            vv1 = *(const uint4*)(vg + (size_t)sr1 * S_ + vo + sc * 8);
        }
        const ushort* ksb = lds_u + cur * 4096;
        const ushort* vsb = lds_u + 8192 + cur * 4096;

        bf16x8 pf[4];
        #pragma unroll
        for (int g = 0; g < 2; ++g) {
            const int key = g * 32 + l31;
            bf16x8 kf[4];
            #pragma unroll
            for (int st = 0; st < 4; ++st)
                kf[st] = *(const bf16x8*)(ksb + key * 64 + (((st * 2 + l5) ^ (key & 7)) * 8));
            f32x16 sc_ = zero16();
            #pragma unroll
            for (int st = 0; st < 4; ++st)
                sc_ = __builtin_amdgcn_mfma_f32_32x32x16_bf16(kf[st], qf[st], sc_, 0, 0, 0);
            uint pr[8];
            #pragma unroll
            for (int rg = 0; rg < 4; ++rg) {
                float p0 = __builtin_amdgcn_exp2f(sc_[rg * 4 + 0]);
                float p1 = __builtin_amdgcn_exp2f(sc_[rg * 4 + 1]);
                float p2 = __builtin_amdgcn_exp2f(sc_[rg * 4 + 2]);
                float p3 = __builtin_amdgcn_exp2f(sc_[rg * 4 + 3]);
                lsum += (p0 + p1) + (p2 + p3);
                pr[2 * rg + 0] = truncpk(p0, p1);
                pr[2 * rg + 1] = truncpk(p2, p3);
            }
            #pragma unroll
            for (int p = 0; p < 2; ++p) {
                lane32swap(pr[4 * p + 0], pr[4 * p + 2]);
                lane32swap(pr[4 * p + 1], pr[4 * p + 3]);
                u32x4 u; u.x = pr[4 * p + 0]; u.y = pr[4 * p + 1];
                u.z = pr[4 * p + 2]; u.w = pr[4 * p + 3];
                pf[g * 2 + p] = __builtin_bit_cast(bf16x8, u);
            }
        }

        #pragma unroll
        for (int dht = 0; dht < 2; ++dht) {
            const int dh = dht * 32 + l31;
            bf16x8 vf[4];
            #pragma unroll
            for (int st = 0; st < 4; ++st)
                vf[st] = *(const bf16x8*)(vsb + dh * 64 + (((st * 2 + l5) ^ (dh & 7)) * 8));
            #pragma unroll
            for (int st = 0; st < 4; ++st)
                O[dht] = __builtin_amdgcn_mfma_f32_32x32x16_bf16(vf[st], pf[st], O[dht], 0, 0, 0);
        }

        if (kt < 31) {
            ushort* kn = lds_u + nxt * 4096;
            ushort* vn = lds_u + 8192 + nxt * 4096;
            *(uint4*)(kn + sr0 * 64 + swz0) = kv0;
            *(uint4*)(kn + sr1 * 64 + swz1) = kv1;
            *(uint4*)(vn + sr0 * 64 + swz0) = vv0;
            *(uint4*)(vn + sr1 * 64 + swz1) = vv1;
        }
    }

    // ---- finalize ----
    lsum += __shfl_xor(lsum, 32);
    const float linv = 1.0f / lsum;
    #pragma unroll
    for (int dht = 0; dht < 2; ++dht)
        #pragma unroll
        for (int i = 0; i < 16; ++i) O[dht][i] *= linv;

    __syncthreads();
    float* ob = (float*)lds_u + w * (32 * 68);
    #pragma unroll
    for (int dht = 0; dht < 2; ++dht)
        #pragma unroll
        for (int rg = 0; rg < 4; ++rg) {
            f32x4 v4;
            v4[0] = O[dht][rg * 4 + 0];
            v4[1] = O[dht][rg * 4 + 1];
            v4[2] = O[dht][rg * 4 + 2];
            v4[3] = O[dht][rg * 4 + 3];
            *(f32x4*)(ob + l31 * 68 + dht * 32 + rg * 8 + l5 * 4) = v4;
        }
    #pragma unroll
    for (int i = 0; i < 8; ++i) {
        const int slot = lane + 64 * i;
        const int r = slot >> 4, c = slot & 15;
        f32x4 v = *(const f32x4*)(ob + r * 68 + c * 4);
        // ob row r holds q-row q0 + r (FIX of R7's s0+r bug)
        *(f32x4*)(out + ((size_t)(b * S_ + q0 + r)) * D_ + h * DH_ + c * 4) = v;
    }
}

extern "C" void kernel_launch(void* const* d_in, const int* in_sizes, int n_in,
                              void* d_out, int out_size, void* d_ws, size_t ws_size,
                              hipStream_t stream) {
    const float* x  = (const float*)d_in[0];
    const float* Wq = (const float*)d_in[1];
    const float* bq = (const float*)d_in[2];
    const float* Wk = (const float*)d_in[3];
    const float* bk = (const float*)d_in[4];
    const float* Wv = (const float*)d_in[5];
    const float* bv = (const float*)d_in[6];
    float* outp = (float*)d_out;

    ushort* Kb  = (ushort*)d_ws;                       // [BH][S][DH] bf16, 8 MB
    ushort* Vtg = Kb + (size_t)BH_ * S_ * DH_;         // [BH][DH][S] bf16, 8 MB
    uint*   cnt = (uint*)((char*)d_ws + 16u * 1024 * 1024);   // 32 counters

    hipMemsetAsync(cnt, 0, 32 * sizeof(uint), stream);
    msa_fused<<<dim3(512), 256, 0, stream>>>(x, Wq, bq, Wk, bk, Wv, bv,
                                             Kb, Vtg, cnt, outp);
}

// Round 9
// 130.554 us; speedup vs baseline: 1.4409x; 1.4409x over previous
//
#include <hip/hip_runtime.h>
#include <math.h>

#define B_ 4
#define S_ 2048
#define D_ 512
#define H_ 8
#define DH_ 64
#define BH_ (B_*H_)
#define SCALE 0.1803368801111243f   // log2(e)/sqrt(64)

typedef __attribute__((ext_vector_type(4)))  float f32x4;
typedef __attribute__((ext_vector_type(16))) float f32x16;
typedef __attribute__((ext_vector_type(8)))  short bf16x8;
typedef __attribute__((ext_vector_type(4)))  uint  u32x4;

__device__ inline uint rnepk(float a, float b) {
    uint ua = __builtin_bit_cast(uint, a), ub = __builtin_bit_cast(uint, b);
    ua += 0x7FFFu + ((ua >> 16) & 1u);
    ub += 0x7FFFu + ((ub >> 16) & 1u);
    return (ua >> 16) | (ub & 0xFFFF0000u);
}
__device__ inline uint truncpk(float lo, float hi) {   // 1 v_perm_b32
    return __builtin_amdgcn_perm(__builtin_bit_cast(uint, hi),
                                 __builtin_bit_cast(uint, lo), 0x07060302u);
}
__device__ inline f32x16 zero16() {
    f32x16 z;
    #pragma unroll
    for (int i = 0; i < 16; ++i) z[i] = 0.f;
    return z;
}
__device__ inline bf16x8 pack8(f32x4 a, f32x4 c) {
    u32x4 u;
    u.x = rnepk(a[0], a[1]); u.y = rnepk(a[2], a[3]);
    u.z = rnepk(c[0], c[1]); u.w = rnepk(c[2], c[3]);
    return __builtin_bit_cast(bf16x8, u);
}

// (lane,lane^32) quad exchange (validated: R6's P-transform passed)
#if __has_builtin(__builtin_amdgcn_permlane32_swap)
__device__ inline void lane32swap(uint& a, uint& b) {
    typedef __attribute__((ext_vector_type(2))) uint u32x2;
    u32x2 r = __builtin_amdgcn_permlane32_swap(a, b, false, false);
    a = r.x; b = r.y;
}
#else
__device__ inline void lane32swap(uint& a, uint& b) {
    const int l5 = (threadIdx.x & 63) >> 5;
    uint send = l5 ? a : b;
    uint recv = __shfl_xor(send, 32);
    uint an = l5 ? recv : a;
    uint bn = l5 ? b : recv;
    a = an; b = bn;
}
#endif

// async global->LDS DMA, 16B/lane: LDS dest = wave-uniform base + lane*16
__device__ inline void dma16(const ushort* g, ushort* l) {
    __builtin_amdgcn_global_load_lds(
        (const __attribute__((address_space(1))) unsigned int*)g,
        (__attribute__((address_space(3))) unsigned int*)l, 16, 0, 0);
}

// ---------------------------------------------------------------------------
// Kernel 1: QKV projection, 32x32x16 MFMA, emitting FRAGMENT-LINEAR layouts:
//   Qf[bh][qt(64)][st(4)][lane*8]   (lane = l5*32+l31: q=qt*32+l31, dh=st*16+l5*8)
//   Kf[bh][kt(32)][g(2)][st(4)][lane*8]  (key=g*32+l31, dh=st*16+l5*8)
//   Vf[bh][kt(32)][dht(2)][st(4)][lane*8] (dh=dht*32+l31, key=st*16+l5*8)
// Every chunk is 64 lanes x 16B so flash can global_load_lds / coalesce-read.
// grid (32, 16), 256 thr. One barrier (V transpose share).
// ---------------------------------------------------------------------------
__global__ __launch_bounds__(256, 2)
void qkv_mfma(const float* __restrict__ x,
              const float* __restrict__ Wq, const float* __restrict__ bq,
              const float* __restrict__ Wk, const float* __restrict__ bk,
              const float* __restrict__ Wv, const float* __restrict__ bv,
              ushort* __restrict__ Qf, ushort* __restrict__ Kf,
              ushort* __restrict__ Vf)
{
    const int bh = blockIdx.x, b = bh >> 3, h = bh & 7;
    const int sblk = blockIdx.y, s0 = sblk * 128;
    const int tid = threadIdx.x;
    const int w = tid >> 6, lane = tid & 63, l31 = lane & 31, l5 = lane >> 5;

    __shared__ __align__(16) ushort bnc[4][2560];    // per-wave [s][e] stride 72
    __shared__ __align__(16) ushort vsh[64 * 136];   // block-shared Vt [dh][s128]
    ushort* mybnc = bnc[w];

    // ---- x fragments straight from global ----
    const int srow = w * 32 + l31;
    const float* xr = x + ((size_t)(b * S_ + s0 + srow)) * D_ + h * DH_;
    bf16x8 xf[4];
    #pragma unroll
    for (int st = 0; st < 4; ++st)
        xf[st] = pack8(*(const f32x4*)(xr + st * 16 + l5 * 8),
                       *(const f32x4*)(xr + st * 16 + l5 * 8 + 4));

    // ---- K: C[e][s] (A=Wk,B=x) -> bounce [s][e] -> fragment emit ----
    {
        bf16x8 wf[2][4];
        #pragma unroll
        for (int et = 0; et < 2; ++et) {
            const float* wr = Wk + h * DH_ * DH_ + (et * 32 + l31) * DH_;
            #pragma unroll
            for (int st = 0; st < 4; ++st)
                wf[et][st] = pack8(*(const f32x4*)(wr + st * 16 + l5 * 8),
                                   *(const f32x4*)(wr + st * 16 + l5 * 8 + 4));
        }
        #pragma unroll
        for (int et = 0; et < 2; ++et) {
            f32x16 acc = zero16();
            #pragma unroll
            for (int st = 0; st < 4; ++st)
                acc = __builtin_amdgcn_mfma_f32_32x32x16_bf16(wf[et][st], xf[st], acc, 0, 0, 0);
            #pragma unroll
            for (int rg = 0; rg < 4; ++rg) {
                float4 b4 = *(const float4*)(bk + h * DH_ + et * 32 + rg * 8 + l5 * 4);
                uint2 pk;
                pk.x = rnepk(acc[rg * 4 + 0] + b4.x, acc[rg * 4 + 1] + b4.y);
                pk.y = rnepk(acc[rg * 4 + 2] + b4.z, acc[rg * 4 + 3] + b4.w);
                *(uint2*)(mybnc + l31 * 72 + et * 32 + rg * 8 + l5 * 4) = pk;
            }
        }
        const int kt = sblk * 2 + (w >> 1), g = w & 1;
        ushort* kd = Kf + (((size_t)(bh * 32 + kt)) * 2 + g) * 2048;
        #pragma unroll
        for (int st = 0; st < 4; ++st) {
            uint4 v = *(const uint4*)(mybnc + l31 * 72 + st * 16 + l5 * 8);
            *(uint4*)(kd + st * 512 + lane * 8) = v;
        }
    }

    // ---- Q: same, with bias+SCALE, emit tile qt = sblk*4 + w ----
    {
        bf16x8 wf[2][4];
        #pragma unroll
        for (int et = 0; et < 2; ++et) {
            const float* wr = Wq + h * DH_ * DH_ + (et * 32 + l31) * DH_;
            #pragma unroll
            for (int st = 0; st < 4; ++st)
                wf[et][st] = pack8(*(const f32x4*)(wr + st * 16 + l5 * 8),
                                   *(const f32x4*)(wr + st * 16 + l5 * 8 + 4));
        }
        #pragma unroll
        for (int et = 0; et < 2; ++et) {
            f32x16 acc = zero16();
            #pragma unroll
            for (int st = 0; st < 4; ++st)
                acc = __builtin_amdgcn_mfma_f32_32x32x16_bf16(wf[et][st], xf[st], acc, 0, 0, 0);
            #pragma unroll
            for (int rg = 0; rg < 4; ++rg) {
                float4 b4 = *(const float4*)(bq + h * DH_ + et * 32 + rg * 8 + l5 * 4);
                uint2 pk;
                pk.x = rnepk((acc[rg * 4 + 0] + b4.x) * SCALE, (acc[rg * 4 + 1] + b4.y) * SCALE);
                pk.y = rnepk((acc[rg * 4 + 2] + b4.z) * SCALE, (acc[rg * 4 + 3] + b4.w) * SCALE);
                *(uint2*)(mybnc + l31 * 72 + et * 32 + rg * 8 + l5 * 4) = pk;
            }
        }
        ushort* qd = Qf + ((size_t)(bh * 64 + sblk * 4 + w)) * 2048;
        #pragma unroll
        for (int st = 0; st < 4; ++st) {
            uint4 v = *(const uint4*)(mybnc + l31 * 72 + st * 16 + l5 * 8);
            *(uint4*)(qd + st * 512 + lane * 8) = v;
        }
    }

    // ---- V: C[s][e] (A=x,B=Wv) -> block-shared Vt[dh][s128] -> frag emit ----
    {
        bf16x8 wf[2][4];
        #pragma unroll
        for (int et = 0; et < 2; ++et) {
            const float* wr = Wv + h * DH_ * DH_ + (et * 32 + l31) * DH_;
            #pragma unroll
            for (int st = 0; st < 4; ++st)
                wf[et][st] = pack8(*(const f32x4*)(wr + st * 16 + l5 * 8),
                                   *(const f32x4*)(wr + st * 16 + l5 * 8 + 4));
        }
        #pragma unroll
        for (int et = 0; et < 2; ++et) {
            f32x16 acc = zero16();
            #pragma unroll
            for (int st = 0; st < 4; ++st)
                acc = __builtin_amdgcn_mfma_f32_32x32x16_bf16(xf[st], wf[et][st], acc, 0, 0, 0);
            const float bb = bv[h * DH_ + et * 32 + l31];
            #pragma unroll
            for (int rg = 0; rg < 4; ++rg) {
                uint2 pk;
                pk.x = rnepk(acc[rg * 4 + 0] + bb, acc[rg * 4 + 1] + bb);
                pk.y = rnepk(acc[rg * 4 + 2] + bb, acc[rg * 4 + 3] + bb);
                // Vt[dh = et*32+l31][s = w*32 + rg*8 + l5*4 + {0..3}]
                *(uint2*)(vsh + (et * 32 + l31) * 136 + w * 32 + rg * 8 + l5 * 4) = pk;
            }
        }
        __syncthreads();
        #pragma unroll
        for (int i = 0; i < 4; ++i) {
            const int c = w * 4 + i;                 // 16 chunks: [ktl][dht][st]
            const int ktl = c >> 3, dht = (c >> 2) & 1, st = c & 3;
            uint4 v = *(const uint4*)(vsh + (dht * 32 + l31) * 136 + ktl * 64 + st * 16 + l5 * 8);
            *(uint4*)(Vf + (((size_t)(bh * 32 + sblk * 2 + ktl)) * 2 + dht) * 2048
                      + st * 512 + lane * 8) = v;
        }
    }
}

// ---------------------------------------------------------------------------
// Kernel 2: flash, 32x32x16 MFMA, 64 q/wave, split-K parity. grid 512 =
// 32 bh x 16 qblk (128 q/block), 4 waves: w0/w1 even K-tiles (q-halves 0/1),
// w2/w3 odd tiles. No online max -> partials merge by pure addition. K/V
// staged via global_load_lds dwordx4 into fragment-linear LDS (zero VALU
// staging); fragment reads are base+lane*16 (conflict-free). One barrier per
// step (2 K-tiles). End: partner merge through LDS, normalize, coalesced out.
// ---------------------------------------------------------------------------
__global__ __launch_bounds__(256, 2)
void flash_mfma(const ushort* __restrict__ Qf, const ushort* __restrict__ Kf,
                const ushort* __restrict__ Vf, float* __restrict__ out)
{
    const int blk = blockIdx.x;
    const int bh = blk & 31, qblk = blk >> 5;
    const int b = bh >> 3, h = bh & 7;
    const int tid = threadIdx.x;
    const int w = tid >> 6, lane = tid & 63, l31 = lane & 31, l5 = lane >> 5;
    const int p = w >> 1, qh = w & 1;    // K-parity, q-half

    // dbuf: buf s at s*16384 ush (32KB): [Kev 4096][Vev 4096][Kod 4096][Vod 4096]
    // epilogue overlays: 2 x (64q x 68 f32) + lsA = 35328 B
    __shared__ __align__(16) ushort lds_u[32768];    // 65536 B

    const ushort* kvsrc = (w & 1) ? (Vf + (size_t)bh * 32 * 4096)
                                  : (Kf + (size_t)bh * 32 * 4096);

    // ---- prologue: DMA step-0 tiles into buf0 (wave w stages region w) ----
    {
        const ushort* gb = kvsrc + (size_t)p * 4096;     // tile = 0+p
        ushort* ld = lds_u + w * 4096;
        #pragma unroll
        for (int i = 0; i < 8; ++i)
            dma16(gb + i * 512 + lane * 8, ld + i * 512);
    }

    // ---- Q B-frags (coalesced from Qf) ----
    bf16x8 qf[2][4];
    #pragma unroll
    for (int qt = 0; qt < 2; ++qt)
        #pragma unroll
        for (int st = 0; st < 4; ++st)
            qf[qt][st] = *(const bf16x8*)(Qf + ((size_t)(bh * 64 + qblk * 4 + qh * 2 + qt)) * 2048
                                          + st * 512 + lane * 8);

    f32x16 O[2][2];                      // [dht][qt], O^T cols q = qt*32+l31
    #pragma unroll
    for (int i = 0; i < 2; ++i)
        #pragma unroll
        for (int j = 0; j < 2; ++j) O[i][j] = zero16();
    float lsum[2] = {0.f, 0.f};

    for (int step = 0; step < 16; ++step) {
        __syncthreads();                 // drains DMAs for buf[cur]
        ushort* cbuf = lds_u + (step & 1) * 16384;
        if (step < 15) {                 // DMA step+1 into other buffer
            const ushort* gb = kvsrc + (size_t)(2 * (step + 1) + p) * 4096;
            ushort* ld = lds_u + ((step + 1) & 1) * 16384 + w * 4096;
            #pragma unroll
            for (int i = 0; i < 8; ++i)
                dma16(gb + i * 512 + lane * 8, ld + i * 512);
        }
        const ushort* kreg = cbuf + p * 8192;
        const ushort* vreg = kreg + 4096;

        // ---- S^T = K.Q^T, exp, pack, quad exchange -> pf ----
        bf16x8 pf[2][4];
        #pragma unroll
        for (int g = 0; g < 2; ++g) {
            bf16x8 kf[4];
            #pragma unroll
            for (int st = 0; st < 4; ++st)
                kf[st] = *(const bf16x8*)(kreg + (g * 4 + st) * 512 + lane * 8);
            #pragma unroll
            for (int qt = 0; qt < 2; ++qt) {
                f32x16 sc_ = zero16();
                #pragma unroll
                for (int st = 0; st < 4; ++st)
                    sc_ = __builtin_amdgcn_mfma_f32_32x32x16_bf16(kf[st], qf[qt][st], sc_, 0, 0, 0);
                uint pr[8];
                #pragma unroll
                for (int rg = 0; rg < 4; ++rg) {
                    float p0 = __builtin_amdgcn_exp2f(sc_[rg * 4 + 0]);
                    float p1 = __builtin_amdgcn_exp2f(sc_[rg * 4 + 1]);
                    float p2 = __builtin_amdgcn_exp2f(sc_[rg * 4 + 2]);
                    float p3 = __builtin_amdgcn_exp2f(sc_[rg * 4 + 3]);
                    lsum[qt] += (p0 + p1) + (p2 + p3);
                    pr[2 * rg + 0] = truncpk(p0, p1);
                    pr[2 * rg + 1] = truncpk(p2, p3);
                }
                #pragma unroll
                for (int pp = 0; pp < 2; ++pp) {
                    lane32swap(pr[4 * pp + 0], pr[4 * pp + 2]);
                    lane32swap(pr[4 * pp + 1], pr[4 * pp + 3]);
                    u32x4 u; u.x = pr[4 * pp + 0]; u.y = pr[4 * pp + 1];
                    u.z = pr[4 * pp + 2]; u.w = pr[4 * pp + 3];
                    pf[qt][g * 2 + pp] = __builtin_bit_cast(bf16x8, u);
                }
            }
        }

        // ---- PV: O^T[dht][qt] += Vt.P^T ----
        #pragma unroll
        for (int dht = 0; dht < 2; ++dht) {
            bf16x8 vf[4];
            #pragma unroll
            for (int st = 0; st < 4; ++st)
                vf[st] = *(const bf16x8*)(vreg + (dht * 4 + st) * 512 + lane * 8);
            #pragma unroll
            for (int qt = 0; qt < 2; ++qt)
                #pragma unroll
                for (int st = 0; st < 4; ++st)
                    O[dht][qt] = __builtin_amdgcn_mfma_f32_32x32x16_bf16(vf[st], pf[qt][st],
                                                                          O[dht][qt], 0, 0, 0);
        }
    }

    // ---- merge parity partners (pure add: no online max), normalize ----
    #pragma unroll
    for (int qt = 0; qt < 2; ++qt) lsum[qt] += __shfl_xor(lsum[qt], 32);

    __syncthreads();                     // all loop reads done before overlay
    float* mb = (float*)lds_u;           // region qh: 64x68 f32; lsA at +8704
    float* reg = mb + qh * 4352;
    float* lsA = mb + 2 * 4352;

    if (p == 1) {                        // odd-parity waves publish partials
        #pragma unroll
        for (int dht = 0; dht < 2; ++dht)
            #pragma unroll
            for (int qt = 0; qt < 2; ++qt)
                #pragma unroll
                for (int rg = 0; rg < 4; ++rg) {
                    f32x4 v4;
                    v4[0] = O[dht][qt][rg * 4 + 0];
                    v4[1] = O[dht][qt][rg * 4 + 1];
                    v4[2] = O[dht][qt][rg * 4 + 2];
                    v4[3] = O[dht][qt][rg * 4 + 3];
                    *(f32x4*)(reg + (qt * 32 + l31) * 68 + dht * 32 + rg * 8 + l5 * 4) = v4;
                }
        if (l5 == 0) {
            #pragma unroll
            for (int qt = 0; qt < 2; ++qt)
                lsA[qh * 64 + qt * 32 + l31] = lsum[qt];
        }
    }
    __syncthreads();
    if (p == 0) {                        // even-parity waves merge + finalize
        float linv[2];
        #pragma unroll
        for (int qt = 0; qt < 2; ++qt)
            linv[qt] = 1.0f / (lsum[qt] + lsA[qh * 64 + qt * 32 + l31]);
        #pragma unroll
        for (int dht = 0; dht < 2; ++dht)
            #pragma unroll
            for (int qt = 0; qt < 2; ++qt)
                #pragma unroll
                for (int rg = 0; rg < 4; ++rg) {
                    float* a = reg + (qt * 32 + l31) * 68 + dht * 32 + rg * 8 + l5 * 4;
                    f32x4 part = *(const f32x4*)a;
                    f32x4 v4;
                    v4[0] = (O[dht][qt][rg * 4 + 0] + part[0]) * linv[qt];
                    v4[1] = (O[dht][qt][rg * 4 + 1] + part[1]) * linv[qt];
                    v4[2] = (O[dht][qt][rg * 4 + 2] + part[2]) * linv[qt];
                    v4[3] = (O[dht][qt][rg * 4 + 3] + part[3]) * linv[qt];
                    *(f32x4*)a = v4;
                }
    }
    __syncthreads();

    // ---- cooperative coalesced store: 128 rows x 16 chunks of 16B ----
    const int q0 = qblk * 128;
    #pragma unroll
    for (int i = 0; i < 8; ++i) {
        const int slot = tid + 256 * i;
        const int r = slot >> 4, c = slot & 15;
        f32x4 v = *(const f32x4*)(mb + (r >> 6) * 4352 + (r & 63) * 68 + c * 4);
        *(f32x4*)(out + ((size_t)(b * S_ + q0 + r)) * D_ + h * DH_ + c * 4) = v;
    }
}

extern "C" void kernel_launch(void* const* d_in, const int* in_sizes, int n_in,
                              void* d_out, int out_size, void* d_ws, size_t ws_size,
                              hipStream_t stream) {
    const float* x  = (const float*)d_in[0];
    const float* Wq = (const float*)d_in[1];
    const float* bq = (const float*)d_in[2];
    const float* Wk = (const float*)d_in[3];
    const float* bk = (const float*)d_in[4];
    const float* Wv = (const float*)d_in[5];
    const float* bv = (const float*)d_in[6];
    float* outp = (float*)d_out;

    ushort* Qf = (ushort*)d_ws;                        // frag-linear, 8 MB
    ushort* Kf = Qf + (size_t)BH_ * S_ * DH_;          // 8 MB
    ushort* Vf = Kf + (size_t)BH_ * S_ * DH_;          // 8 MB

    qkv_mfma<<<dim3(BH_, S_ / 128), 256, 0, stream>>>(x, Wq, bq, Wk, bk, Wv, bv,
                                                      Qf, Kf, Vf);
    flash_mfma<<<dim3(32 * 16), 256, 0, stream>>>(Qf, Kf, Vf, outp);
}